// Round 1
// baseline (394.304 us; speedup 1.0000x reference)
//
#include <hip/hip_runtime.h>
#include <hip/hip_bf16.h>

typedef __attribute__((ext_vector_type(8))) short short8;
typedef __attribute__((ext_vector_type(4))) float floatx4;

#define NSEQ 16
#define SEQ 128
#define DIM 256
#define HID 256
#define K3H 768
#define K2D 512

__device__ __forceinline__ float frcp(float x) { return __builtin_amdgcn_rcpf(x); }
__device__ __forceinline__ float fsigmoid(float x) { return frcp(1.f + __expf(-x)); }
__device__ __forceinline__ float ftanh(float x) {
    // 1 - 2/(1+e^{2x}); exp->inf => 1, exp->0 => -1. No NaN.
    return 1.f - 2.f * frcp(1.f + __expf(2.f * x));
}
__device__ __forceinline__ unsigned short bf16bits(float v) {
    unsigned u = __builtin_bit_cast(unsigned, v);
    unsigned r = (u + 0x7FFFu + ((u >> 16) & 1u)) >> 16;
    return (unsigned short)r;
}

// ---------------- K1: left = x@w1, right = x@w2 ----------------
__global__ __launch_bounds__(256) void k1_leftright(
        const float* __restrict__ x, const float* __restrict__ w1,
        const float* __restrict__ w2, float* __restrict__ left,
        float* __restrict__ right) {
    __shared__ __align__(16) float xs[8][DIM];
    const int tid = threadIdx.x;
    const int r0 = blockIdx.x * 8;
    #pragma unroll
    for (int i = 0; i < 8; ++i) xs[i][tid] = x[(r0 + i) * DIM + tid];
    __syncthreads();
    float accL[8], accR[8];
    #pragma unroll
    for (int i = 0; i < 8; ++i) { accL[i] = 0.f; accR[i] = 0.f; }
    #pragma unroll 4
    for (int d = 0; d < DIM; ++d) {
        float wa = w1[d * DIM + tid];
        float wb = w2[d * DIM + tid];
        #pragma unroll
        for (int i = 0; i < 8; ++i) {
            float xv = xs[i][d];
            accL[i] = fmaf(xv, wa, accL[i]);
            accR[i] = fmaf(xv, wb, accR[i]);
        }
    }
    #pragma unroll
    for (int i = 0; i < 8; ++i) {
        left[(r0 + i) * DIM + tid]  = accL[i];
        right[(r0 + i) * DIM + tid] = accR[i];
    }
}

// ---------------- K2: scores (tanh, v3 dot), softmax, c = score@x ----------------
__global__ __launch_bounds__(128) void k2_attn(
        const float* __restrict__ x, const float* __restrict__ left,
        const float* __restrict__ right, const float* __restrict__ bias,
        const float* __restrict__ v3, float* __restrict__ cout) {
    __shared__ __align__(16) float lm[DIM];
    __shared__ __align__(16) float v3s[DIM];
    __shared__ float p[SEQ];
    __shared__ float red[2];
    const int tid = threadIdx.x;      // 0..127 (= n)
    const int lane = tid & 63;
    const int wid = tid >> 6;         // 0..1
    const int bm = blockIdx.x;        // 0..2047
    const int b = bm >> 7;            // sequence index

    const float* lrow = left + bm * DIM;
    #pragma unroll
    for (int q = 0; q < 2; ++q) {
        int d = tid + q * 128;
        lm[d]  = lrow[d] + bias[d];
        v3s[d] = v3[d];
    }
    __syncthreads();

    const float4* rrow = reinterpret_cast<const float4*>(right + (b * SEQ + tid) * DIM);
    const float4* lm4  = reinterpret_cast<const float4*>(lm);
    const float4* vv4  = reinterpret_cast<const float4*>(v3s);
    float s = 0.f;
    for (int d4 = 0; d4 < DIM / 4; ++d4) {
        float4 rv = rrow[d4];
        float4 lv = lm4[d4];
        float4 vv = vv4[d4];
        s = fmaf(ftanh(lv.x + rv.x), vv.x, s);
        s = fmaf(ftanh(lv.y + rv.y), vv.y, s);
        s = fmaf(ftanh(lv.z + rv.z), vv.z, s);
        s = fmaf(ftanh(lv.w + rv.w), vv.w, s);
    }
    // softmax over the 128 threads
    float m = s;
    #pragma unroll
    for (int off = 32; off >= 1; off >>= 1) m = fmaxf(m, __shfl_xor(m, off, 64));
    if (lane == 0) red[wid] = m;
    __syncthreads();
    m = fmaxf(red[0], red[1]);
    float e = __expf(s - m);
    float t = e;
    #pragma unroll
    for (int off = 32; off >= 1; off >>= 1) t += __shfl_xor(t, off, 64);
    __syncthreads();
    if (lane == 0) red[wid] = t;
    __syncthreads();
    float denom = red[0] + red[1];
    p[tid] = e * frcp(denom);
    __syncthreads();

    // c[bm, d] = sum_n p[n] * x[b, n, d]
    const float* xb = x + b * SEQ * DIM;
    float c0 = 0.f, c1 = 0.f;
    #pragma unroll 4
    for (int n = 0; n < SEQ; ++n) {
        float pn = p[n];
        c0 = fmaf(pn, xb[n * DIM + tid], c0);
        c1 = fmaf(pn, xb[n * DIM + tid + 128], c1);
    }
    cout[bm * DIM + tid]       = c0;
    cout[bm * DIM + tid + 128] = c1;
}

// ---------------- K3: xp = [x, c] @ gru_kernel + b_in ----------------
__global__ __launch_bounds__(256) void k3_xproj(
        const float* __restrict__ x, const float* __restrict__ c,
        const float* __restrict__ gk, const float* __restrict__ gbias,
        float* __restrict__ xp) {
    __shared__ __align__(16) float xc[8][K2D];
    const int tid = threadIdx.x;
    const int r0 = blockIdx.x * 8;
    #pragma unroll
    for (int i = 0; i < 8; ++i) {
        xc[i][tid]       = x[(r0 + i) * DIM + tid];
        xc[i][tid + 256] = c[(r0 + i) * DIM + tid];
    }
    __syncthreads();
    float acc[8][3];
    #pragma unroll
    for (int i = 0; i < 8; ++i) {
        acc[i][0] = gbias[tid];
        acc[i][1] = gbias[256 + tid];
        acc[i][2] = gbias[512 + tid];
    }
    #pragma unroll 2
    for (int k = 0; k < K2D; ++k) {
        float g0 = gk[k * K3H + tid];
        float g1 = gk[k * K3H + 256 + tid];
        float g2 = gk[k * K3H + 512 + tid];
        #pragma unroll
        for (int i = 0; i < 8; ++i) {
            float xv = xc[i][k];
            acc[i][0] = fmaf(xv, g0, acc[i][0]);
            acc[i][1] = fmaf(xv, g1, acc[i][1]);
            acc[i][2] = fmaf(xv, g2, acc[i][2]);
        }
    }
    #pragma unroll
    for (int i = 0; i < 8; ++i) {
        xp[(r0 + i) * K3H + tid]       = acc[i][0];
        xp[(r0 + i) * K3H + 256 + tid] = acc[i][1];
        xp[(r0 + i) * K3H + 512 + tid] = acc[i][2];
    }
}

// ---------------- K4: GRU recurrence, weights resident in VGPRs as MFMA B-frags ----------------
// 1 block per sequence, 512 threads (8 waves). Wave w owns output cols [w*96, w*96+96)
// as 6 N-tiles of 16; K=256 as 8 chunks of 32 -> B-frags [6][8] of short8 (192 VGPRs).
__global__ __launch_bounds__(512, 2) void k4_gru(
        const float* __restrict__ rec, const float* __restrict__ gbias,
        const float* __restrict__ xp, float* __restrict__ out) {
    __shared__ __align__(16) float ws[16 * K3H];      // 48KB staging
    __shared__ float rp[K3H];
    __shared__ float brec[K3H];
    __shared__ float h32[HID];
    __shared__ __align__(16) unsigned short hbf[HID];
    const int tid  = threadIdx.x;
    const int lane = tid & 63;
    const int wv   = tid >> 6;     // 0..7
    const int seq  = blockIdx.x;   // 0..15

    for (int idx = tid; idx < K3H; idx += 512) brec[idx] = gbias[K3H + idx];
    if (tid < HID) { h32[tid] = 0.f; hbf[tid] = 0; }

    short8 Bf[6][8];
    // Preload rec_kernel as bf16 B-fragments. 16 parts of 16 rows each.
    #pragma unroll
    for (int part = 0; part < 16; ++part) {
        #pragma unroll
        for (int q = 0; q < 6; ++q) {
            int fi = q * 512 + tid;   // 3072 float4 = 16*768 floats
            reinterpret_cast<float4*>(ws)[fi] =
                reinterpret_cast<const float4*>(rec + part * 16 * K3H)[fi];
        }
        __syncthreads();
        const int kc = part >> 1, half = part & 1;
        #pragma unroll
        for (int tt = 0; tt < 6; ++tt) {
            int col = wv * 96 + tt * 16 + (lane & 15);
            #pragma unroll
            for (int j = 0; j < 8; ++j) {
                int r = (lane >> 4) * 8 + j;          // k within chunk, 0..31
                if ((r >> 4) == half) {
                    Bf[tt][kc][j] = (short)bf16bits(ws[(r & 15) * K3H + col]);
                }
            }
        }
        __syncthreads();
    }

    const float* xps = xp + seq * SEQ * K3H;
    float* outs = out + seq * SEQ * HID;

    for (int s = 0; s < SEQ; ++s) {
        float xz = 0.f, xr = 0.f, xh = 0.f;
        if (tid < HID) {   // prefetch gate inputs; latency hidden under MFMAs
            xz = xps[s * K3H + tid];
            xr = xps[s * K3H + 256 + tid];
            xh = xps[s * K3H + 512 + tid];
        }
        floatx4 C[6];
        #pragma unroll
        for (int tt = 0; tt < 6; ++tt) C[tt] = (floatx4){0.f, 0.f, 0.f, 0.f};
        #pragma unroll
        for (int kc = 0; kc < 8; ++kc) {
            short8 a = {0, 0, 0, 0, 0, 0, 0, 0};
            if ((lane & 15) == 0)   // A row 0 = h (M=1)
                a = *reinterpret_cast<const short8*>(&hbf[kc * 32 + (lane >> 4) * 8]);
            #pragma unroll
            for (int tt = 0; tt < 6; ++tt)
                C[tt] = __builtin_amdgcn_mfma_f32_16x16x32_bf16(a, Bf[tt][kc], C[tt], 0, 0, 0);
        }
        if (lane < 16) {   // C/D: col=lane&15, row=(lane>>4)*4+reg; row0 -> lanes 0-15 reg0
            #pragma unroll
            for (int tt = 0; tt < 6; ++tt)
                rp[wv * 96 + tt * 16 + lane] = C[tt][0];
        }
        __syncthreads();
        if (tid < HID) {
            float rz = rp[tid] + brec[tid];
            float rr = rp[256 + tid] + brec[256 + tid];
            float rh = rp[512 + tid] + brec[512 + tid];
            float z  = fsigmoid(xz + rz);
            float r  = fsigmoid(xr + rr);
            float hh = ftanh(xh + r * rh);
            float hn = z * h32[tid] + (1.f - z) * hh;
            outs[s * HID + tid] = hn;
            h32[tid] = hn;
            hbf[tid] = bf16bits(hn);
        }
        __syncthreads();
    }
}

extern "C" void kernel_launch(void* const* d_in, const int* in_sizes, int n_in,
                              void* d_out, int out_size, void* d_ws, size_t ws_size,
                              hipStream_t stream) {
    const float* feat = (const float*)d_in[0];
    const float* w1   = (const float*)d_in[1];
    const float* w2   = (const float*)d_in[2];
    const float* bias = (const float*)d_in[3];
    const float* v3   = (const float*)d_in[4];
    const float* gk   = (const float*)d_in[5];
    const float* grk  = (const float*)d_in[6];
    const float* gb   = (const float*)d_in[7];
    float* out = (float*)d_out;

    char* wsb = (char*)d_ws;
    float* left  = (float*)(wsb);
    float* right = (float*)(wsb + (size_t)2 * 1024 * 1024);
    float* cbuf  = (float*)(wsb + (size_t)4 * 1024 * 1024);
    float* xp    = (float*)(wsb + (size_t)6 * 1024 * 1024);

    k1_leftright<<<2048 / 8, 256, 0, stream>>>(feat, w1, w2, left, right);
    k2_attn<<<NSEQ * SEQ, 128, 0, stream>>>(feat, left, right, bias, v3, cbuf);
    k3_xproj<<<2048 / 8, 256, 0, stream>>>(feat, cbuf, gk, gb, xp);
    k4_gru<<<NSEQ, 512, 0, stream>>>(grk, gb, xp, out);
}